// Round 3
// baseline (292.012 us; speedup 1.0000x reference)
//
#include <hip/hip_runtime.h>
#include <math.h>

// BoundaryFocalLoss: B=128, T=200000, f32 inputs, i32 targets, f32 mask -> scalar f32.
// ~307 MB footprint; L3 absorbs ~half (FETCH ~157 MB) so floor ~35-45 us.
//
// R1: 654 us = same-address atomic serialization -> partials + 2nd kernel (124 us).
// R2 post-mortem: latency-bound, not BW-bound (16% HBM, 40% occupancy, 4 blocks/CU,
// VGPR=24 so no MLP). R3: 2560 blocks (10/CU), 8 elems/thread (2x int4 pairs, 8
// independent loads in flight), branchless halo via clamp-replication (edge
// transition bits self-cancel, matching reference zero-padding).

#define B_DIM 128
#define T_DIM 200000

constexpr int BLOCK           = 256;
constexpr int GROUPS_PER_ROW  = T_DIM / 4;          // 50000 int4/float4 groups
constexpr int CHUNKS_PER_ROW  = T_DIM / 8;          // 25000 8-elem chunks
constexpr int BLOCKS_X        = 20;                 // blocks per row
constexpr int ROW_STRIDE      = BLOCKS_X * BLOCK;   // 5120 chunks per sweep
constexpr int NUM_ITERS       = (CHUNKS_PER_ROW + ROW_STRIDE - 1) / ROW_STRIDE; // 5
constexpr int NUM_PARTIALS    = BLOCKS_X * B_DIM;   // 2560

__global__ __launch_bounds__(BLOCK) void bfl_main(
    const float* __restrict__ inputs,
    const int*   __restrict__ targets,
    const float* __restrict__ mask,
    float2*      __restrict__ partials)   // [NUM_PARTIALS] = (loss_sum, mask_sum)
{
    const int b = blockIdx.y;
    const long long row = (long long)b * T_DIM;
    const float4* __restrict__ inp4 = (const float4*)(inputs + row);
    const float4* __restrict__ msk4 = (const float4*)(mask + row);
    const int4*   __restrict__ tgt4 = (const int4*)(targets + row);

    float lsum = 0.0f, msum = 0.0f;

    #pragma unroll
    for (int iter = 0; iter < NUM_ITERS; ++iter) {
        const int chunk = iter * ROW_STRIDE + blockIdx.x * BLOCK + threadIdx.x;
        if (chunk < CHUNKS_PER_ROW) {
            const int q = chunk * 2;            // int4-group index

            // 8 independent 16B loads — issue all before compute for MLP
            const float4 x0 = inp4[q];
            const float4 x1 = inp4[q + 1];
            const float4 m0 = msk4[q];
            const float4 m1 = msk4[q + 1];
            const int4   c0 = tgt4[q];
            const int4   c1 = tgt4[q + 1];
            const int4   pv = (q > 0)
                ? tgt4[q - 1] : make_int4(c0.x, c0.x, c0.x, c0.x);
            const int4   nx = (q + 2 < GROUPS_PER_ROW)
                ? tgt4[q + 2] : make_int4(c1.w, c1.w, c1.w, c1.w);

            // tg[k] = targets[t0 - 4 + k], k = 0..14 (halo -4..+10).
            // Clamp-replication makes edge transition bits compare-equal -> 0,
            // matching the reference's zero-padded trans[0] — no index checks.
            const int tg[15] = {pv.x, pv.y, pv.z, pv.w,
                                c0.x, c0.y, c0.z, c0.w,
                                c1.x, c1.y, c1.z, c1.w,
                                nx.x, nx.y, nx.z};

            unsigned mbits = 0u;
            #pragma unroll
            for (int k = 1; k <= 14; ++k) {
                if (tg[k] != tg[k - 1]) mbits |= (1u << k);
            }

            const float xs[8] = {x0.x, x0.y, x0.z, x0.w, x1.x, x1.y, x1.z, x1.w};
            const float ms[8] = {m0.x, m0.y, m0.z, m0.w, m1.x, m1.y, m1.z, m1.w};

            #pragma unroll
            for (int ii = 0; ii < 8; ++ii) {
                const float x  = xs[ii];
                const float mm = ms[ii];
                const bool pos = ((float)tg[4 + ii]) > 0.5f;

                const float smoothed = pos ? 0.975f : 0.025f;  // pos*(1-ls)+ls/2
                // boundary[i] = OR of trans bits (ii+1 .. ii+7) <-> j in [i-3,i+3]
                const float w = ((mbits >> (ii + 1)) & 0x7Fu) ? 5.0f : 1.0f;

                // ea = exp(-|x|); |sigmoid(x)-0.5| = |1-ea| / (2*(1+ea))
                const float ea   = __expf(-fabsf(x));
                const float opea = 1.0f + ea;
                const float r    = 1.0f / opea;
                const float adaptive = 1.0f - 0.5f * fabsf(1.0f - ea) * r;

                const float bce = fmaxf(x, 0.0f) - x * smoothed + __logf(opea);
                const float pt  = __expf(-bce);
                const float alpha_w = pos ? 0.25f : 0.75f;
                const float om = 1.0f - pt;

                lsum += alpha_w * om * om * bce * w * adaptive * mm;
                msum += mm;
            }
        }
    }

    // wave (64-lane) butterfly reduction
    #pragma unroll
    for (int off = 32; off > 0; off >>= 1) {
        lsum += __shfl_xor(lsum, off);
        msum += __shfl_xor(msum, off);
    }

    __shared__ float sL[BLOCK / 64];
    __shared__ float sM[BLOCK / 64];
    const int wave = threadIdx.x >> 6;
    const int lane = threadIdx.x & 63;
    if (lane == 0) { sL[wave] = lsum; sM[wave] = msum; }
    __syncthreads();

    if (threadIdx.x == 0) {
        float bl = 0.0f, bm = 0.0f;
        #pragma unroll
        for (int i = 0; i < BLOCK / 64; ++i) { bl += sL[i]; bm += sM[i]; }
        partials[blockIdx.y * BLOCKS_X + blockIdx.x] = make_float2(bl, bm);
    }
}

__global__ __launch_bounds__(BLOCK) void bfl_reduce(
    const float2* __restrict__ partials,
    float*        __restrict__ out)
{
    float ls = 0.0f, ms = 0.0f;
    #pragma unroll
    for (int i = 0; i < NUM_PARTIALS / BLOCK; ++i) {
        const float2 p = partials[i * BLOCK + threadIdx.x];
        ls += p.x; ms += p.y;
    }

    #pragma unroll
    for (int off = 32; off > 0; off >>= 1) {
        ls += __shfl_xor(ls, off);
        ms += __shfl_xor(ms, off);
    }

    __shared__ float sL[BLOCK / 64];
    __shared__ float sM[BLOCK / 64];
    const int wave = threadIdx.x >> 6;
    const int lane = threadIdx.x & 63;
    if (lane == 0) { sL[wave] = ls; sM[wave] = ms; }
    __syncthreads();

    if (threadIdx.x == 0) {
        float bl = 0.0f, bm = 0.0f;
        #pragma unroll
        for (int i = 0; i < BLOCK / 64; ++i) { bl += sL[i]; bm += sM[i]; }
        out[0] = (bm > 0.0f) ? (bl / bm) : 0.0f;
    }
}

extern "C" void kernel_launch(void* const* d_in, const int* in_sizes, int n_in,
                              void* d_out, int out_size, void* d_ws, size_t ws_size,
                              hipStream_t stream) {
    const float* inputs   = (const float*)d_in[0];
    const int*   targets  = (const int*)d_in[1];
    const float* mask     = (const float*)d_in[2];
    float*       out      = (float*)d_out;
    float2*      partials = (float2*)d_ws;

    dim3 grid(BLOCKS_X, B_DIM);
    bfl_main<<<grid, BLOCK, 0, stream>>>(inputs, targets, mask, partials);
    bfl_reduce<<<1, BLOCK, 0, stream>>>(partials, out);
}